// Round 12
// baseline (381.479 us; speedup 1.0000x reference)
//
#include <hip/hip_runtime.h>
#include <math.h>

#define NINST 4096

typedef _Float16 half8 __attribute__((ext_vector_type(8)));
typedef _Float16 half4 __attribute__((ext_vector_type(4)));
typedef float floatx4 __attribute__((ext_vector_type(4)));

// ---------------------------------------------------------------------------
// xform_w12: weight transforms + tl zero-init.
// w1 (36,3,4,4) -> w1t [48 oc][64], k = ky*16+kx*4+ic
// w2 (48,36,3,3) -> w2t [3 ky][48 oc][128], k = kx*40+ic (k<120)
// ---------------------------------------------------------------------------
__global__ void xform_w12(const float* __restrict__ w1, const float* __restrict__ w2,
                          _Float16* __restrict__ w1t, _Float16* __restrict__ w2t,
                          float* __restrict__ tl) {
  for (int i = blockIdx.x * 256 + threadIdx.x; i < 48 * 64; i += gridDim.x * 256) {
    const int oc = i >> 6, k = i & 63;
    const int ky = k >> 4, r = k & 15, kx = r >> 2, ic = r & 3;
    float v = 0.f;
    if (oc < 36 && ic < 3) v = w1[((oc * 3 + ic) * 4 + ky) * 4 + kx];
    w1t[i] = (_Float16)v;
  }
  for (int i = blockIdx.x * 256 + threadIdx.x; i < 3 * 48 * 128; i += gridDim.x * 256) {
    const int ky = i / 6144, r = i % 6144;
    const int oc = r >> 7, k = r & 127;
    float v = 0.f;
    if (k < 120) {
      const int kx = k / 40, ic = k % 40;
      if (ic < 36) v = w2[((oc * 36 + ic) * 3 + ky) * 3 + kx];
    }
    w2t[i] = (_Float16)v;
  }
  for (int i = blockIdx.x * 256 + threadIdx.x; i < 10 * NINST; i += gridDim.x * 256)
    tl[i] = 0.f;
}

// ---------------------------------------------------------------------------
// MFMA conv, TWO instances per block (2048 blocks): 3 barriers per 2 inst
// (was 3 per 1), both x-loads in flight together. Static acc indices (r8).
// LDS: x 16KB + h1 30.7KB = 46.7KB -> 3 blocks/CU. h2 staging overlays the
// dead x region after the h1 barrier; emb write = contiguous 432 half8.
// Pool-aligned m-map: m = window*4 + (dy*2+dx) -> C-quad regs = 2x2 window.
// ---------------------------------------------------------------------------
__launch_bounds__(256, 2)
__global__ void conv_fused(const float* __restrict__ x,
                           const _Float16* __restrict__ w1t_g,
                           const _Float16* __restrict__ w2t_g,
                           const float* __restrict__ b1, const float* __restrict__ b2,
                           _Float16* __restrict__ emb) {
  __shared__ __align__(16) _Float16 x_s[8192];      // 2 x [1024 pix][4 ch]
  __shared__ __align__(16) _Float16 h1_s[15712];    // 2 x (196*40 + 16 pad)

  const int n0 = blockIdx.x * 2, tid = threadIdx.x;
  const int lane = tid & 63, wave = tid >> 6;
  const int quad = lane >> 4, l15 = lane & 15;

  // ---- stage x for both instances: fp32 NCHW -> fp16 channel-last ----
  {
#pragma unroll
    for (int inst = 0; inst < 2; inst++) {
      const float* xb = x + (size_t)(n0 + inst) * 3072 + tid * 4;
      floatx4 xr0 = __builtin_nontemporal_load((const floatx4*)(xb));
      floatx4 xr1 = __builtin_nontemporal_load((const floatx4*)(xb + 1024));
      floatx4 xr2 = __builtin_nontemporal_load((const floatx4*)(xb + 2048));
      half8 pk0, pk1;
      pk0[0] = (_Float16)xr0[0]; pk0[1] = (_Float16)xr1[0]; pk0[2] = (_Float16)xr2[0]; pk0[3] = (_Float16)0.f;
      pk0[4] = (_Float16)xr0[1]; pk0[5] = (_Float16)xr1[1]; pk0[6] = (_Float16)xr2[1]; pk0[7] = (_Float16)0.f;
      pk1[0] = (_Float16)xr0[2]; pk1[1] = (_Float16)xr1[2]; pk1[2] = (_Float16)xr2[2]; pk1[3] = (_Float16)0.f;
      pk1[4] = (_Float16)xr0[3]; pk1[5] = (_Float16)xr1[3]; pk1[6] = (_Float16)xr2[3]; pk1[7] = (_Float16)0.f;
      *(half8*)&x_s[inst * 4096 + tid * 16] = pk0;
      *(half8*)&x_s[inst * 4096 + tid * 16 + 8] = pk1;
    }
    if (tid < 16) { h1_s[7840 + tid] = (_Float16)0.f; h1_s[7856 + 7840 + tid] = (_Float16)0.f; }
  }
  __syncthreads();

  // ---- conv1 both instances: M=784, N=48(36), K=64(48) -> h1 pooled+relu ----
  {
    half8 bc[2][3];
#pragma unroll
    for (int c = 0; c < 2; c++)
#pragma unroll
      for (int nt = 0; nt < 3; nt++)
        bc[c][nt] = *(const half8*)&w1t_g[(nt * 16 + l15) * 64 + c * 32 + quad * 8];
    float bia[3];
#pragma unroll
    for (int nt = 0; nt < 3; nt++) {
      const int oc = nt * 16 + l15;
      bia[nt] = (oc < 36) ? b1[oc] : 0.f;
    }
#pragma unroll
    for (int inst = 0; inst < 2; inst++) {
      const _Float16* xin = x_s + inst * 4096;
      _Float16* h1o = h1_s + inst * 7856;
      for (int mt = wave; mt < 49; mt += 4) {
        const int mA = mt * 16 + l15;
        const int ppA = mA >> 2, dA = mA & 3;
        const int yA = 2 * (ppA / 14) + (dA >> 1);
        const int xA = 2 * (ppA % 14) + (dA & 1);
        floatx4 a1[3];
#pragma unroll
        for (int nt = 0; nt < 3; nt++)
#pragma unroll
          for (int r = 0; r < 4; r++) a1[nt][r] = 0.f;
#pragma unroll
        for (int c = 0; c < 2; c++) {
          const int row = yA + c * 2 + (quad >> 1);
          const half8 af = *(const half8*)&xin[row * 128 + xA * 4 + (quad & 1) * 8];
#pragma unroll
          for (int nt = 0; nt < 3; nt++)
            a1[nt] = __builtin_amdgcn_mfma_f32_16x16x32_f16(af, bc[c][nt], a1[nt], 0, 0, 0);
        }
        const int ppC = mt * 4 + quad;
#pragma unroll
        for (int nt = 0; nt < 3; nt++) {
          const int oc = nt * 16 + l15;
          float v = fmaxf(fmaxf(a1[nt][0], a1[nt][1]), fmaxf(a1[nt][2], a1[nt][3])) + bia[nt];
          v = fmaxf(v, 0.f);
          if (oc < 40) h1o[ppC * 40 + oc] = (_Float16)v;  // oc 36..39 write pad zeros
        }
      }
    }
  }
  __syncthreads();   // h1 ready; x region dead from here

  // ---- conv2 + pool per instance (acc regs reused). Static acc indices. ----
  float bia2[3];
#pragma unroll
  for (int nt = 0; nt < 3; nt++) bia2[nt] = b2[nt * 16 + l15];

#pragma unroll
  for (int inst = 0; inst < 2; inst++) {
    const _Float16* h1i = h1_s + inst * 7856;
    _Float16* h2o = x_s + inst * 1728;   // overlay dead x region
    floatx4 acc2[3][3];
#pragma unroll
    for (int a = 0; a < 3; a++)
#pragma unroll
      for (int j = 0; j < 3; j++)
#pragma unroll
        for (int r = 0; r < 4; r++) acc2[a][j][r] = 0.f;

    for (int ky = 0; ky < 3; ky++) {
      half8 bc2[4][3];
#pragma unroll
      for (int c = 0; c < 4; c++)
#pragma unroll
        for (int nt = 0; nt < 3; nt++)
          bc2[c][nt] = *(const half8*)&w2t_g[ky * 6144 + (nt * 16 + l15) * 128 + c * 32 + quad * 8];
#pragma unroll
      for (int mi = 0; mi < 3; mi++) {
        const int mt = wave + 4 * mi;
        if (mt < 9) {
          const int mA = mt * 16 + l15;
          const int ppA = mA >> 2, dA = mA & 3;
          const int y2 = 2 * (ppA / 6) + (dA >> 1);
          const int x2 = 2 * (ppA % 6) + (dA & 1);
          const int rb = ((y2 + ky) * 14 + x2) * 40;
#pragma unroll
          for (int c = 0; c < 4; c++) {
            const half8 af = *(const half8*)&h1i[rb + c * 32 + quad * 8];
#pragma unroll
            for (int nt = 0; nt < 3; nt++)
              acc2[mi][nt] = __builtin_amdgcn_mfma_f32_16x16x32_f16(af, bc2[c][nt], acc2[mi][nt], 0, 0, 0);
          }
        }
      }
    }
#pragma unroll
    for (int mi = 0; mi < 3; mi++) {
      const int mt = wave + 4 * mi;
      if (mt < 9) {
        const int ppC = mt * 4 + quad;
#pragma unroll
        for (int nt = 0; nt < 3; nt++) {
          const int oc = nt * 16 + l15;
          float v = fmaxf(fmaxf(acc2[mi][nt][0], acc2[mi][nt][1]),
                          fmaxf(acc2[mi][nt][2], acc2[mi][nt][3])) + bia2[nt];
          v = fmaxf(v, 0.f);
          h2o[oc * 36 + ppC] = (_Float16)v;
        }
      }
    }
  }
  __syncthreads();   // epilogue staged (LDS drain only)
  {
    half8* dst = (half8*)(emb + (size_t)n0 * 1728);    // 2 instances contiguous
    const half8* src = (const half8*)x_s;
    for (int i = tid; i < 432; i += 256) dst[i] = src[i];
  }
}

// ---------------------------------------------------------------------------
// fp16-A x fp32-B MFMA GEMM: C = act(A.B^T + bias). BM=64, BN=64, BK=64,
// wave tile 32x32 (2x2 MFMA), single-barrier ping-pong dbuf, inline B cast.
// LDS 38.5KB -> 4 blocks/CU; grids 512-1024 blocks (2-4/CU).
// FUSE: instead of writing C, dot tanh'd rows with 10 templates (LDS-staged
// slice) and atomicAdd per-row partials into tl[10][4096]  (proto+templ fusion).
// ---------------------------------------------------------------------------
template <int ACT, bool FUSE>
__launch_bounds__(256, 2)
__global__ void gemm_h(const _Float16* __restrict__ A, const float* __restrict__ Bf,
                       const float* __restrict__ bias, _Float16* __restrict__ C,
                       int K, int lda, int ldb, int ldc,
                       const float* __restrict__ tmpl, float* __restrict__ tl) {
  __shared__ __align__(16) _Float16 As[2][64 * 72];
  __shared__ __align__(16) _Float16 Bs[2][64 * 72];
  __shared__ float tmpl_s[640];
  const int tid = threadIdx.x;
  const int m0 = blockIdx.y * 64, n0 = blockIdx.x * 64;
  const int lane = tid & 63, wave = tid >> 6;
  const int quad = lane >> 4, l15 = lane & 15;
  const int wm = (wave >> 1) * 32, wn = (wave & 1) * 32;
  const int srow = tid >> 2, scol = (tid & 3) * 16;   // 64 rows x 4 chunks of 16

  if (FUSE) {
    for (int i = tid; i < 640; i += 256)
      tmpl_s[i] = tmpl[(i >> 6) * 1024 + n0 + (i & 63)];
  }

  const _Float16* Ap = A + (size_t)(m0 + srow) * lda + scol;
  const float* Bp = Bf + (size_t)(n0 + srow) * ldb + scol;

  half8 av0 = *(const half8*)(Ap);
  half8 av1 = *(const half8*)(Ap + 8);
  floatx4 bv0 = *(const floatx4*)(Bp);
  floatx4 bv1 = *(const floatx4*)(Bp + 4);
  floatx4 bv2 = *(const floatx4*)(Bp + 8);
  floatx4 bv3 = *(const floatx4*)(Bp + 12);

  floatx4 acc[2][2];
#pragma unroll
  for (int a = 0; a < 2; a++)
#pragma unroll
    for (int j = 0; j < 2; j++)
#pragma unroll
      for (int r = 0; r < 4; r++) acc[a][j][r] = 0.f;

  int buf = 0;
  for (int k0 = 0; k0 < K; k0 += 64) {
    *(half8*)&As[buf][srow * 72 + scol] = av0;
    *(half8*)&As[buf][srow * 72 + scol + 8] = av1;
    {
      half8 bh0, bh1;
      bh0[0] = (_Float16)bv0[0]; bh0[1] = (_Float16)bv0[1];
      bh0[2] = (_Float16)bv0[2]; bh0[3] = (_Float16)bv0[3];
      bh0[4] = (_Float16)bv1[0]; bh0[5] = (_Float16)bv1[1];
      bh0[6] = (_Float16)bv1[2]; bh0[7] = (_Float16)bv1[3];
      bh1[0] = (_Float16)bv2[0]; bh1[1] = (_Float16)bv2[1];
      bh1[2] = (_Float16)bv2[2]; bh1[3] = (_Float16)bv2[3];
      bh1[4] = (_Float16)bv3[0]; bh1[5] = (_Float16)bv3[1];
      bh1[6] = (_Float16)bv3[2]; bh1[7] = (_Float16)bv3[3];
      *(half8*)&Bs[buf][srow * 72 + scol] = bh0;
      *(half8*)&Bs[buf][srow * 72 + scol + 8] = bh1;
    }
    __syncthreads();
    if (k0 + 64 < K) {
      av0 = *(const half8*)(Ap + k0 + 64);
      av1 = *(const half8*)(Ap + k0 + 64 + 8);
      bv0 = *(const floatx4*)(Bp + k0 + 64);
      bv1 = *(const floatx4*)(Bp + k0 + 64 + 4);
      bv2 = *(const floatx4*)(Bp + k0 + 64 + 8);
      bv3 = *(const floatx4*)(Bp + k0 + 64 + 12);
    }
#pragma unroll
    for (int ks = 0; ks < 64; ks += 32) {
      half8 af[2], bf[2];
#pragma unroll
      for (int mt = 0; mt < 2; mt++)
        af[mt] = *(const half8*)&As[buf][(wm + mt * 16 + l15) * 72 + ks + quad * 8];
#pragma unroll
      for (int nt = 0; nt < 2; nt++)
        bf[nt] = *(const half8*)&Bs[buf][(wn + nt * 16 + l15) * 72 + ks + quad * 8];
#pragma unroll
      for (int mt = 0; mt < 2; mt++)
#pragma unroll
        for (int nt = 0; nt < 2; nt++)
          acc[mt][nt] = __builtin_amdgcn_mfma_f32_16x16x32_f16(af[mt], bf[nt], acc[mt][nt], 0, 0, 0);
    }
    buf ^= 1;
  }

  // epilogue: act(acc + bias) in place
#pragma unroll
  for (int nt = 0; nt < 2; nt++) {
    const float bcolv = bias[n0 + wn + nt * 16 + l15];
#pragma unroll
    for (int mt = 0; mt < 2; mt++)
#pragma unroll
      for (int r = 0; r < 4; r++) {
        float v = acc[mt][nt][r] + bcolv;
        if (ACT == 1) v = fmaxf(v, 0.f);
        if (ACT == 2) v = tanhf(v);
        acc[mt][nt][r] = v;
      }
  }

  if (!FUSE) {
#pragma unroll
    for (int nt = 0; nt < 2; nt++) {
      const int col = n0 + wn + nt * 16 + l15;
#pragma unroll
      for (int mt = 0; mt < 2; mt++)
#pragma unroll
        for (int r = 0; r < 4; r++)
          C[(size_t)(m0 + wm + mt * 16 + quad * 4 + r) * ldc + col] = (_Float16)acc[mt][nt][r];
    }
  } else {
    // per-row dot with 10 templates: reduce over this block's 64 cols
#pragma unroll
    for (int t = 0; t < 10; t++) {
      const float t0 = tmpl_s[t * 64 + wn + l15];
      const float t1 = tmpl_s[t * 64 + wn + 16 + l15];
#pragma unroll
      for (int mt = 0; mt < 2; mt++)
#pragma unroll
        for (int r = 0; r < 4; r++) {
          float p = acc[mt][0][r] * t0 + acc[mt][1][r] * t1;
          p += __shfl_xor(p, 1, 64);
          p += __shfl_xor(p, 2, 64);
          p += __shfl_xor(p, 4, 64);
          p += __shfl_xor(p, 8, 64);
          if (l15 == 0)
            atomicAdd(&tl[t * NINST + m0 + wm + mt * 16 + quad * 4 + r], p);
        }
    }
  }
}

// ---------------------------------------------------------------------------
// Neighborhood attention: one wave per instance, half8-vectorized loads
// (lane l holds elements [8l, 8l+8) of each 512-half row).
// ---------------------------------------------------------------------------
__launch_bounds__(256)
__global__ void nbhd_k(_Float16* __restrict__ H2, const _Float16* __restrict__ T) {
  const int wid = (blockIdx.x * 256 + threadIdx.x) >> 6;
  const int lane = threadIdx.x & 63;
  const int r = wid >> 6, c = wid & 63;
  const half8 hv = *(const half8*)&H2[(size_t)wid * 1024 + lane * 8];

  float sv[8];
  int jv[8];
  bool ok[8];
  int q = 0;
#pragma unroll
  for (int dr = -1; dr <= 1; dr++)
#pragma unroll
    for (int dc = -1; dc <= 1; dc++) {
      if (dr == 0 && dc == 0) continue;
      const int rr = r + dr, cc = c + dc;
      const bool v = (rr >= 0) && (rr < 64) && (cc >= 0) && (cc < 64);
      const int j = v ? (rr * 64 + cc) : wid;
      const half8 tv = *(const half8*)&T[(size_t)j * 512 + lane * 8];
      float s = 0.f;
#pragma unroll
      for (int u = 0; u < 8; u++) s = fmaf((float)hv[u], (float)tv[u], s);
#pragma unroll
      for (int off = 32; off > 0; off >>= 1) s += __shfl_xor(s, off, 64);
      sv[q] = v ? s : -3.4e38f;
      jv[q] = j;
      ok[q] = v;
      q++;
    }

  float m = sv[0];
#pragma unroll
  for (int a = 1; a < 8; a++) m = fmaxf(m, sv[a]);
  float e[8], den = 0.f;
#pragma unroll
  for (int a = 0; a < 8; a++) {
    e[a] = ok[a] ? expf(sv[a] - m) : 0.f;
    den += e[a];
  }
  const float inv = 1.f / den;

  float ov[8];
#pragma unroll
  for (int u = 0; u < 8; u++) ov[u] = 0.f;
#pragma unroll
  for (int a = 0; a < 8; a++) {
    const float al = e[a] * inv;
    const half8 hj = *(const half8*)&H2[(size_t)jv[a] * 1024 + lane * 8];
#pragma unroll
    for (int u = 0; u < 8; u++) ov[u] = fmaf(al, (float)hj[u], ov[u]);
  }
  half8 pk;
#pragma unroll
  for (int u = 0; u < 8; u++) pk[u] = (_Float16)ov[u];
  *(half8*)&H2[(size_t)wid * 1024 + 512 + lane * 8] = pk;
}

// ---------------------------------------------------------------------------
// Per-template softmax over N=4096; also zeros embs rows (for embs_k atomics)
// ---------------------------------------------------------------------------
__launch_bounds__(256)
__global__ void softmax_rows(const float* __restrict__ tl, float* __restrict__ betas,
                             float* __restrict__ embs) {
  const int t = blockIdx.x, tid = threadIdx.x;
  __shared__ float red[256];
  for (int i = tid; i < 1024; i += 256) embs[t * 1024 + i] = 0.f;
  const float* row = tl + t * NINST;
  float m = -3.4e38f;
  for (int i = tid; i < NINST; i += 256) m = fmaxf(m, row[i]);
  red[tid] = m;
  __syncthreads();
  for (int s = 128; s > 0; s >>= 1) {
    if (tid < s) red[tid] = fmaxf(red[tid], red[tid + s]);
    __syncthreads();
  }
  m = red[0];
  __syncthreads();
  float sum = 0.f;
  for (int i = tid; i < NINST; i += 256) sum += expf(row[i] - m);
  red[tid] = sum;
  __syncthreads();
  for (int s = 128; s > 0; s >>= 1) {
    if (tid < s) red[tid] += red[tid + s];
    __syncthreads();
  }
  const float inv = 1.f / red[0];
  for (int i = tid; i < NINST; i += 256) betas[t * NINST + i] = expf(row[i] - m) * inv;
}

// ---------------------------------------------------------------------------
// embs[t,k] += sum_{n in slice} betas[t,n] * H2h[n,k]
// ---------------------------------------------------------------------------
__launch_bounds__(256)
__global__ void embs_k(const float* __restrict__ betas, const _Float16* __restrict__ H2,
                       float* __restrict__ embs) {
  const int k = blockIdx.x * 256 + threadIdx.x;
  const int nbase = blockIdx.y * 256;
  float acc[10];
#pragma unroll
  for (int t = 0; t < 10; t++) acc[t] = 0.f;
  for (int n = nbase; n < nbase + 256; n++) {
    const float v = (float)H2[(size_t)n * 1024 + k];
#pragma unroll
    for (int t = 0; t < 10; t++) acc[t] = fmaf(betas[t * NINST + n], v, acc[t]);
  }
#pragma unroll
  for (int t = 0; t < 10; t++) atomicAdd(&embs[t * 1024 + k], acc[t]);
}

// ---------------------------------------------------------------------------
// ga1_k: hh[t,d] = tanh(embs[t,:].ga1_w[d,:] + ga1_b[d]).  One block per d.
// ---------------------------------------------------------------------------
__launch_bounds__(256)
__global__ void ga1_k(const float* __restrict__ embs, const float* __restrict__ ga1_w,
                      const float* __restrict__ ga1_b, float* __restrict__ hh) {
  const int d = blockIdx.x, tid = threadIdx.x;
  const int wave = tid >> 6, lane = tid & 63;
  __shared__ float part[4][10];

  float acc[10];
#pragma unroll
  for (int t = 0; t < 10; t++) acc[t] = 0.f;
#pragma unroll
  for (int kk = 0; kk < 4; kk++) {
    const int k = kk * 256 + tid;
    const float wv = ga1_w[(size_t)d * 1024 + k];
#pragma unroll
    for (int t = 0; t < 10; t++) acc[t] = fmaf(wv, embs[t * 1024 + k], acc[t]);
  }
#pragma unroll
  for (int t = 0; t < 10; t++) {
#pragma unroll
    for (int off = 32; off > 0; off >>= 1) acc[t] += __shfl_xor(acc[t], off, 64);
  }
  if (lane == 0) {
#pragma unroll
    for (int t = 0; t < 10; t++) part[wave][t] = acc[t];
  }
  __syncthreads();
  if (tid < 10) {
    const float s = part[0][tid] + part[1][tid] + part[2][tid] + part[3][tid];
    hh[tid * 128 + d] = tanhf(s + ga1_b[d]);
  }
}

// ---------------------------------------------------------------------------
// ga2_k: g = hh.ga2_w + b -> softmax gammas (to ws) -> M -> Y_prob/Y_hat.
// ---------------------------------------------------------------------------
__launch_bounds__(256)
__global__ void ga2_k(const float* __restrict__ hh, const float* __restrict__ ga2_w,
                      const float* __restrict__ ga2_b, const float* __restrict__ embs,
                      const float* __restrict__ cls_w, const float* __restrict__ cls_b,
                      float* __restrict__ gam_ws, float* __restrict__ out) {
  __shared__ float g_s[10], gam_s[10];
  __shared__ float red[256];
  const int tid = threadIdx.x;
  const int wave = tid >> 6, lane = tid & 63;

  if (wave == 0) {
    for (int t = 0; t < 10; t++) {
      float s = hh[t * 128 + lane] * ga2_w[lane] + hh[t * 128 + 64 + lane] * ga2_w[64 + lane];
#pragma unroll
      for (int off = 32; off > 0; off >>= 1) s += __shfl_xor(s, off, 64);
      if (lane == 0) g_s[t] = s + ga2_b[0];
    }
  }
  __syncthreads();
  if (tid == 0) {
    float m = g_s[0];
    for (int t = 1; t < 10; t++) m = fmaxf(m, g_s[t]);
    float sum = 0.f;
    for (int t = 0; t < 10; t++) sum += expf(g_s[t] - m);
    for (int t = 0; t < 10; t++) {
      gam_s[t] = expf(g_s[t] - m) / sum;
      gam_ws[t] = gam_s[t];
    }
  }
  __syncthreads();

  float partl = 0.f;
  for (int k = tid; k < 1024; k += 256) {
    float a = 0.f;
#pragma unroll
    for (int t = 0; t < 10; t++) a = fmaf(gam_s[t], embs[t * 1024 + k], a);
    partl = fmaf(a, cls_w[k], partl);
  }
  red[tid] = partl;
  __syncthreads();
  for (int s = 128; s > 0; s >>= 1) {
    if (tid < s) red[tid] += red[tid + s];
    __syncthreads();
  }
  if (tid == 0) {
    const float z = red[0] + cls_b[0];
    const float yp = 1.f / (1.f + expf(-z));
    out[0] = yp;
    out[1] = (yp >= 0.5f) ? 1.f : 0.f;
  }
}

// ---------------------------------------------------------------------------
// A[n] = sum_t gammas[t] * betas[t,n]   (16 blocks)
// ---------------------------------------------------------------------------
__launch_bounds__(256)
__global__ void a_k(const float* __restrict__ betas, const float* __restrict__ gam,
                    float* __restrict__ outA) {
  const int n = blockIdx.x * 256 + threadIdx.x;
  float a = 0.f;
#pragma unroll
  for (int t = 0; t < 10; t++) a = fmaf(gam[t], betas[t * NINST + n], a);
  outA[n] = a;
}

// ---------------------------------------------------------------------------
extern "C" void kernel_launch(void* const* d_in, const int* in_sizes, int n_in,
                              void* d_out, int out_size, void* d_ws, size_t ws_size,
                              hipStream_t stream) {
  const float* x       = (const float*)d_in[0];
  const float* w1      = (const float*)d_in[2];
  const float* b1      = (const float*)d_in[3];
  const float* w2      = (const float*)d_in[4];
  const float* b2      = (const float*)d_in[5];
  const float* fc1_w   = (const float*)d_in[6];
  const float* fc1_b   = (const float*)d_in[7];
  const float* fc2_w   = (const float*)d_in[8];
  const float* fc2_b   = (const float*)d_in[9];
  const float* nbr_w   = (const float*)d_in[10];
  const float* nbr_b   = (const float*)d_in[11];
  const float* tmpl    = (const float*)d_in[12];
  const float* proto_w = (const float*)d_in[13];
  const float* proto_b = (const float*)d_in[14];
  const float* ga1_w   = (const float*)d_in[15];
  const float* ga1_b   = (const float*)d_in[16];
  const float* ga2_w   = (const float*)d_in[17];
  const float* ga2_b   = (const float*)d_in[18];
  const float* cls_w   = (const float*)d_in[19];
  const float* cls_b   = (const float*)d_in[20];
  float* out = (float*)d_out;

  char* w = (char*)d_ws;
  _Float16* embh = (_Float16*)w;  w += (size_t)4096 * 1728 * 2;
  _Float16* H1h  = (_Float16*)w;  w += (size_t)4096 * 512 * 2;
  _Float16* H2h  = (_Float16*)w;  w += (size_t)4096 * 1024 * 2;
  _Float16* TbH  = (_Float16*)w;  w += (size_t)4096 * 512 * 2;
  _Float16* w1tG = (_Float16*)w;  w += (size_t)48 * 64 * 2;
  _Float16* w2tG = (_Float16*)w;  w += (size_t)3 * 48 * 128 * 2;
  float* tl   = (float*)w;        w += (size_t)10 * NINST * 4;
  float* bet  = (float*)w;        w += (size_t)10 * NINST * 4;
  float* embs = (float*)w;        w += (size_t)10 * 1024 * 4;
  float* hhw  = (float*)w;        w += (size_t)10 * 128 * 4;
  float* gam  = (float*)w;        w += 256;

  xform_w12<<<64, 256, 0, stream>>>(w1, w2, w1tG, w2tG, tl);
  conv_fused<<<NINST / 2, 256, 0, stream>>>(x, w1tG, w2tG, b1, b2, embh);

  gemm_h<1, false><<<dim3(8, 64), 256, 0, stream>>>(embh, fc1_w, fc1_b, H1h,
                                                    1728, 1728, 1728, 512, nullptr, nullptr);
  gemm_h<1, false><<<dim3(8, 64), 256, 0, stream>>>(H1h, fc2_w, fc2_b, H2h,
                                                    512, 512, 512, 1024, nullptr, nullptr);
  gemm_h<2, false><<<dim3(8, 64), 256, 0, stream>>>(H2h, nbr_w, nbr_b, TbH,
                                                    512, 1024, 512, 512, nullptr, nullptr);
  nbhd_k<<<1024, 256, 0, stream>>>(H2h, TbH);
  // proto GEMM with fused template scoring (PH never materialized)
  gemm_h<2, true><<<dim3(16, 64), 256, 0, stream>>>(H2h, proto_w, proto_b, nullptr,
                                                    1024, 1024, 1024, 0, tmpl, tl);
  softmax_rows<<<10, 256, 0, stream>>>(tl, bet, embs);
  embs_k<<<dim3(4, 16), 256, 0, stream>>>(bet, H2h, embs);
  ga1_k<<<128, 256, 0, stream>>>(embs, ga1_w, ga1_b, hhw);
  ga2_k<<<1, 256, 0, stream>>>(hhw, ga2_w, ga2_b, embs, cls_w, cls_b, gam, out);
  a_k<<<16, 256, 0, stream>>>(bet, gam, out + 2);
}